// Round 14
// baseline (433.303 us; speedup 1.0000x reference)
//
#include <hip/hip_runtime.h>

#define E_NUM 12000
#define D_DIM 6272
#define H_DIM 256
#define M1 24000

typedef __attribute__((ext_vector_type(8))) short short8;
typedef __attribute__((ext_vector_type(8))) __bf16 bf16x8;
typedef __attribute__((ext_vector_type(4))) float f32x4;

__device__ __forceinline__ float silu_f(float x) {
  return x / (1.0f + __expf(-x));
}

__device__ __forceinline__ bf16x8 ld_frag(const short* p) {
  return __builtin_bit_cast(bf16x8, *(const short8*)p);
}

__device__ __forceinline__ bf16x8 cvt8(f32x4 a, f32x4 b) {
  bf16x8 r;
#pragma unroll
  for (int j = 0; j < 4; ++j) {
    r[j] = (__bf16)a[j];
    r[4 + j] = (__bf16)b[j];
  }
  return r;
}

__device__ __forceinline__ void gll16(const void* g, void* l) {
  __builtin_amdgcn_global_load_lds(
      (const __attribute__((address_space(1))) void*)g,
      (__attribute__((address_space(3))) void*)l, 16, 0, 0);
}

// ---- P1 pack: P1[(kt*256 + col)*32 + p] = bf(W1[kt*32 + p][col]) ----
__global__ void pack_p1(const float* __restrict__ W1, short* __restrict__ P1) {
  const int kt = blockIdx.x;    // 0..195
  const int col = threadIdx.x;  // 0..255
  const float* src = W1 + (size_t)kt * 32 * H_DIM + col;
  short* dst = P1 + ((size_t)kt * H_DIM + col) * 32;
#pragma unroll
  for (int c = 0; c < 4; ++c) {
    short8 s;
#pragma unroll
    for (int j = 0; j < 8; ++j)
      s[j] = __builtin_bit_cast(short, (__bf16)src[(size_t)(c * 8 + j) * H_DIM]);
    *(short8*)(dst + c * 8) = s;
  }
}

// ---- P2 pack: P2[(kt*D_DIM + col)*32 + p] = bf(W2[kt*32 + p][col]) ----
__global__ void pack_p2(const float* __restrict__ W2, short* __restrict__ P2) {
  const int kt = blockIdx.y;                       // 0..7
  const int col = blockIdx.x * 128 + threadIdx.x;  // 0..6271
  const float* src = W2 + (size_t)kt * 32 * D_DIM + col;
  short* dst = P2 + ((size_t)kt * D_DIM + col) * 32;
#pragma unroll
  for (int c = 0; c < 4; ++c) {
    short8 s;
#pragma unroll
    for (int j = 0; j < 8; ++j)
      s[j] = __builtin_bit_cast(short, (__bf16)src[(size_t)(c * 8 + j) * D_DIM]);
    *(short8*)(dst + c * 8) = s;
  }
}

// ============================ FUSED kernel ============================
// Block = 16 edges. Phase 1 (v13 body): x-rows [16 ne; 16 ori] @ P1 -> gated h
// in LDS (bf16, swizzled). One barrier. Phase 2 (barrier-free): h @ P2 ->
// silu + combine halves -> out rows e0..e0+15. Grid 750, 256 thr, 48KB LDS.
#define G1_NT 49
__launch_bounds__(256, 3)
__global__ void fused_kernel(const float* __restrict__ node_embed,
                             const float* __restrict__ x_edge_c,
                             const float* __restrict__ ori,
                             const short* __restrict__ P1,
                             const float* __restrict__ b1,
                             const short* __restrict__ P2,
                             const float* __restrict__ b2,
                             float* __restrict__ out) {
  __shared__ __align__(16) float Abuf[2][32 * 128];  // 2 x 16 KB (phase 1)
  __shared__ __align__(16) short hls[32 * 256];      // 16 KB gated h (bf16)

  const int t = threadIdx.x;
  const int wn = t >> 6;
  const int lane = t & 63;
  const int l15 = lane & 15;
  const int lq = lane >> 4;
  const int e0 = blockIdx.x * 16;

  // ================= PHASE 1 (v13 body, rows: 16 ne + 16 ori) =================
  // staging: round j (0..3): dest float idx = t*4 + j*1024 -> row (t>>5)+8j, phys
  // chunk t&31; logical chunk = (t&24)|((t&7)^(t>>5)) (row&7 == t>>5 all rounds).
  // rounds 0,1: node_embed rows 0-15; rounds 2,3: ori rows 16-31.
  const int aswz_chunk = ((t & 24) | ((t & 7) ^ (t >> 5)));
  const float* aNE = node_embed + (size_t)(e0 + (t >> 5)) * D_DIM + aswz_chunk * 4;
  const float* aOR = ori + (size_t)(e0 + (t >> 5)) * D_DIM + aswz_chunk * 4;

  const short* bbase = P1 + (size_t)(wn * 64 + l15) * 32 + lq * 8;
  const int asw = l15 & 7;

  f32x4 acc[2][4];
#pragma unroll
  for (int m = 0; m < 2; ++m)
#pragma unroll
    for (int n = 0; n < 4; ++n) acc[m][n] = (f32x4){0.f, 0.f, 0.f, 0.f};

#define G1_STAGE(IT, BUF)                                                 \
  do {                                                                    \
    const float* _n = aNE + (size_t)(IT)*128;                             \
    const float* _o = aOR + (size_t)(IT)*128;                             \
    gll16(_n, &Abuf[BUF][t * 4]);                                         \
    gll16(_n + (size_t)8 * D_DIM, &Abuf[BUF][t * 4 + 1024]);              \
    gll16(_o, &Abuf[BUF][t * 4 + 2048]);                                  \
    gll16(_o + (size_t)8 * D_DIM, &Abuf[BUF][t * 4 + 3072]);              \
  } while (0)

  G1_STAGE(0, 0);
  __syncthreads();

  int cur = 0;
  for (int it = 0; it < G1_NT; ++it) {
    const int nxt = cur ^ 1;
    bf16x8 bq[4][4];
    {
      const short* bs = bbase + (size_t)it * 32768;
#pragma unroll
      for (int ks = 0; ks < 4; ++ks)
#pragma unroll
        for (int n = 0; n < 4; ++n) bq[ks][n] = ld_frag(bs + ks * 8192 + n * 512);
    }
    if (it + 1 < G1_NT) G1_STAGE(it + 1, nxt);

    const float* Ap = &Abuf[cur][0];
#pragma unroll
    for (int ks = 0; ks < 4; ++ks) {
      bf16x8 af[2];
#pragma unroll
      for (int m = 0; m < 2; ++m) {
        const int row = m * 16 + l15;
        const int c_lo = 8 * ks + 2 * lq;
        const int pl = (c_lo & 24) | ((c_lo & 7) ^ asw);
        const int ph = (c_lo & 24) | (((c_lo + 1) & 7) ^ asw);
        f32x4 lo = *(const f32x4*)(Ap + row * 128 + pl * 4);
        f32x4 hi = *(const f32x4*)(Ap + row * 128 + ph * 4);
        af[m] = cvt8(lo, hi);
      }
#pragma unroll
      for (int m = 0; m < 2; ++m)
#pragma unroll
        for (int n = 0; n < 4; ++n)
          acc[m][n] = __builtin_amdgcn_mfma_f32_16x16x32_bf16(af[m], bq[ks][n],
                                                              acc[m][n], 0, 0, 0);
    }
    __syncthreads();
    cur = nxt;
  }
#undef G1_STAGE

  // ---- phase-1 epilogue: bias + silu + gate -> h in LDS (bf16, swizzled) ----
  // h[row][col]: 16B-chunk c (=col>>3) of row r stored at phys (c&16)|((c&15)^(r&15))
#pragma unroll
  for (int n = 0; n < 4; ++n) {
    const int col = wn * 64 + n * 16 + l15;
    const float b1v = b1[col];
    const int hc = col >> 3;
#pragma unroll
    for (int m = 0; m < 2; ++m) {
#pragma unroll
      for (int i = 0; i < 4; ++i) {
        const int row = m * 16 + lq * 4 + i;
        const int e = e0 + (row & 15);
        float v = acc[m][n][i] + b1v;
        v = silu_f(v) * x_edge_c[(size_t)e * H_DIM + col];
        const int pc = (hc & 16) | ((hc & 15) ^ (row & 15));
        hls[row * 256 + pc * 8 + (col & 7)] = __builtin_bit_cast(short, (__bf16)v);
      }
    }
  }
  __syncthreads();  // h complete; phase 2 is barrier-free

  // ================= PHASE 2: h[32][256] @ P2 -> out[16][6272] =================
  // wave wn owns d-cols [wn*1568, +1568) in 49 chunks of 32. M-frags: m=0 ne rows,
  // m=1 ori rows -> combined in epilogue. No barriers; 12 desynced waves/CU.
  const int dstart = wn * 1568;
  for (int c = 0; c < 49; ++c) {
    const int dbase = dstart + c * 32;
    // batch-issue all 16 B-frag loads for this chunk (1KB contiguous each, L2)
    bf16x8 bq2[8][2];
#pragma unroll
    for (int kk = 0; kk < 8; ++kk)
#pragma unroll
      for (int n = 0; n < 2; ++n)
        bq2[kk][n] =
            ld_frag(P2 + ((size_t)kk * D_DIM + dbase + n * 16 + l15) * 32 + lq * 8);

    f32x4 a2[2][2];
#pragma unroll
    for (int m = 0; m < 2; ++m)
#pragma unroll
      for (int n = 0; n < 2; ++n) a2[m][n] = (f32x4){0.f, 0.f, 0.f, 0.f};

#pragma unroll
    for (int kk = 0; kk < 8; ++kk) {
      const int c2 = kk * 4 + lq;
      const int p2 = (c2 & 16) | ((c2 & 15) ^ l15);
      bf16x8 af0 = ld_frag(&hls[(0 * 16 + l15) * 256 + p2 * 8]);
      bf16x8 af1 = ld_frag(&hls[(1 * 16 + l15) * 256 + p2 * 8]);
      a2[0][0] = __builtin_amdgcn_mfma_f32_16x16x32_bf16(af0, bq2[kk][0], a2[0][0], 0, 0, 0);
      a2[0][1] = __builtin_amdgcn_mfma_f32_16x16x32_bf16(af0, bq2[kk][1], a2[0][1], 0, 0, 0);
      a2[1][0] = __builtin_amdgcn_mfma_f32_16x16x32_bf16(af1, bq2[kk][0], a2[1][0], 0, 0, 0);
      a2[1][1] = __builtin_amdgcn_mfma_f32_16x16x32_bf16(af1, bq2[kk][1], a2[1][1], 0, 0, 0);
    }

    // chunk epilogue: bias + silu + combine ne/ori -> fp32 out
#pragma unroll
    for (int n = 0; n < 2; ++n) {
      const int col = dbase + n * 16 + l15;
      const float b2v = b2[col];
#pragma unroll
      for (int i = 0; i < 4; ++i) {
        const int e = e0 + lq * 4 + i;
        out[(size_t)e * D_DIM + col] =
            silu_f(a2[0][n][i] + b2v) + silu_f(a2[1][n][i] + b2v);
      }
    }
  }
}

extern "C" void kernel_launch(void* const* d_in, const int* in_sizes, int n_in,
                              void* d_out, int out_size, void* d_ws, size_t ws_size,
                              hipStream_t stream) {
  const float* node_embed = (const float*)d_in[0];
  const float* x_edge_c = (const float*)d_in[1];
  const float* ori = (const float*)d_in[2];
  const float* W1 = (const float*)d_in[3];
  const float* b1 = (const float*)d_in[4];
  const float* W2 = (const float*)d_in[5];
  const float* b2 = (const float*)d_in[6];
  float* out_p = (float*)d_out;

  char* ws = (char*)d_ws;
  short* P1 = (short*)ws;              // [196][256][32] bf16 = 3,211,264 B
  short* P2 = (short*)(ws + 3211264);  // [8][6272][32] bf16 = 3,211,264 B

  pack_p1<<<dim3(D_DIM / 32), 256, 0, stream>>>(W1, P1);
  pack_p2<<<dim3(D_DIM / 128, 8), 128, 0, stream>>>(W2, P2);

  fused_kernel<<<dim3(E_NUM / 16), 256, 0, stream>>>(node_embed, x_edge_c, ori, P1,
                                                     b1, P2, b2, out_p);
}